// Round 1
// baseline (629.348 us; speedup 1.0000x reference)
//
#include <hip/hip_runtime.h>
#include <hip/hip_bf16.h>

// Problem: out[8192, 4096] (fp32) = x[8192, 4096] (fp32) @ W[4096, 4096] (int8 values in int32 container)
#define M_DIM 8192
#define N_DIM 4096
#define K_DIM 4096

typedef __attribute__((ext_vector_type(8))) short short8;
typedef __attribute__((ext_vector_type(4))) float floatx4;

__device__ __forceinline__ unsigned short f2bf(float f) {
    union { float f; unsigned int u; } cv; cv.f = f;
    unsigned int u = cv.u;
    return (unsigned short)((u + 0x7fffu + ((u >> 16) & 1u)) >> 16);
}

// ---------------- pre-pass 1: x fp32 -> bf16 ----------------
__global__ __launch_bounds__(256) void cvt_x_kernel(const float* __restrict__ x,
                                                    unsigned short* __restrict__ y) {
    // each thread converts 8 floats -> 8 bf16 (16B store)
    unsigned int i = blockIdx.x * 256u + threadIdx.x;
    const float4* p = (const float4*)x + (size_t)i * 2;
    float4 v0 = p[0];
    float4 v1 = p[1];
    uint4 o;
    o.x = (unsigned int)f2bf(v0.x) | ((unsigned int)f2bf(v0.y) << 16);
    o.y = (unsigned int)f2bf(v0.z) | ((unsigned int)f2bf(v0.w) << 16);
    o.z = (unsigned int)f2bf(v1.x) | ((unsigned int)f2bf(v1.y) << 16);
    o.w = (unsigned int)f2bf(v1.z) | ((unsigned int)f2bf(v1.w) << 16);
    ((uint4*)y)[i] = o;
}

// ---------------- pre-pass 2: W int32 [K][N] -> bf16 W^T [N][K] ----------------
__global__ __launch_bounds__(256) void wt_cvt_kernel(const int* __restrict__ W,
                                                     unsigned short* __restrict__ WT) {
    __shared__ __attribute__((aligned(16))) unsigned short tile[64][80]; // pad 16 to spread banks, keep 16B align
    const int t  = threadIdx.x;
    const int tn = blockIdx.x;   // N/64 tiles
    const int tk = blockIdx.y;   // K/64 tiles
    const int r = t >> 2;              // 0..63
    const int c = (t & 3) << 4;        // 0,16,32,48

    // load 16 int32 (coalesced), convert to bf16, store to LDS [k_local][n_local]
    const int* src = W + (size_t)(tk * 64 + r) * N_DIM + tn * 64 + c;
#pragma unroll
    for (int q = 0; q < 4; ++q) {
        int4 v = ((const int4*)src)[q];
        unsigned int lo = (unsigned int)f2bf((float)v.x) | ((unsigned int)f2bf((float)v.y) << 16);
        unsigned int hi = (unsigned int)f2bf((float)v.z) | ((unsigned int)f2bf((float)v.w) << 16);
        uint2 pk; pk.x = lo; pk.y = hi;
        *(uint2*)&tile[r][c + q * 4] = pk;
    }
    __syncthreads();

    // write W^T row n = tn*64 + r, k columns tk*64 + c .. +16
    unsigned short ov[16];
#pragma unroll
    for (int j = 0; j < 16; ++j) ov[j] = tile[c + j][r];
    unsigned short* dst = WT + (size_t)(tn * 64 + r) * K_DIM + tk * 64 + c;
    uint4 o0, o1;
    o0.x = ov[0] | ((unsigned int)ov[1] << 16);
    o0.y = ov[2] | ((unsigned int)ov[3] << 16);
    o0.z = ov[4] | ((unsigned int)ov[5] << 16);
    o0.w = ov[6] | ((unsigned int)ov[7] << 16);
    o1.x = ov[8] | ((unsigned int)ov[9] << 16);
    o1.y = ov[10] | ((unsigned int)ov[11] << 16);
    o1.z = ov[12] | ((unsigned int)ov[13] << 16);
    o1.w = ov[14] | ((unsigned int)ov[15] << 16);
    ((uint4*)dst)[0] = o0;
    ((uint4*)dst)[1] = o1;
}

// ---------------- main GEMM (m97 structure): A bf16 [M][K], BT bf16 [N][K] ----------------
__global__ __launch_bounds__(256) void gemm_pp(const unsigned short* __restrict__ A,
                                               const unsigned short* __restrict__ BT,
                                               float* __restrict__ C) {
    __shared__ __attribute__((aligned(16))) unsigned short sA[128 * 32];
    __shared__ __attribute__((aligned(16))) unsigned short sB[128 * 32];

    const int t    = threadIdx.x;
    const int lane = t & 63;
    const int wave = t >> 6;
    const int bn   = blockIdx.x;   // N/128 = 32
    const int bm   = blockIdx.y;   // M/128 = 64
    const int waveM = (wave >> 1) * 64;
    const int waveN = (wave & 1) * 64;

    // --- staging addresses (16B per lane, row-major tiles, BK=32) ---
    const int sr = t >> 2;             // 0..63
    const int sc = (t & 3) << 3;       // element col: 0,8,16,24
    const unsigned short* gA0 = A + (size_t)(bm * 128 + sr) * K_DIM + sc;
    const unsigned short* gA1 = gA0 + (size_t)64 * K_DIM;
    const unsigned short* gB0 = BT + (size_t)(bn * 128 + sr) * K_DIM + sc;
    const unsigned short* gB1 = gB0 + (size_t)64 * K_DIM;
    // wave-uniform LDS destinations (HW adds lane*16)
    unsigned short* lA0 = sA + wave * 512;
    unsigned short* lA1 = sA + 2048 + wave * 512;
    unsigned short* lB0 = sB + wave * 512;
    unsigned short* lB1 = sB + 2048 + wave * 512;

    // --- fragment read addresses ---
    const int fr = lane & 15;
    const int fk = (lane >> 4) << 3;   // 0,8,16,24
    const unsigned short* fA = sA + (waveM + fr) * 32 + fk;
    const unsigned short* fB = sB + (waveN + fr) * 32 + fk;

    floatx4 acc[4][4];
#pragma unroll
    for (int i = 0; i < 4; ++i)
#pragma unroll
        for (int j = 0; j < 4; ++j) acc[i][j] = (floatx4){0.f, 0.f, 0.f, 0.f};

    for (int k0 = 0; k0 < K_DIM; k0 += 32) {
        __builtin_amdgcn_global_load_lds((const __attribute__((address_space(1))) void*)gA0,
                                         (__attribute__((address_space(3))) void*)lA0, 16, 0, 0);
        __builtin_amdgcn_global_load_lds((const __attribute__((address_space(1))) void*)gA1,
                                         (__attribute__((address_space(3))) void*)lA1, 16, 0, 0);
        __builtin_amdgcn_global_load_lds((const __attribute__((address_space(1))) void*)gB0,
                                         (__attribute__((address_space(3))) void*)lB0, 16, 0, 0);
        __builtin_amdgcn_global_load_lds((const __attribute__((address_space(1))) void*)gB1,
                                         (__attribute__((address_space(3))) void*)lB1, 16, 0, 0);
        gA0 += 32; gA1 += 32; gB0 += 32; gB1 += 32;
        __syncthreads();  // compiler drains vmcnt before barrier

        short8 a[4], b[4];
#pragma unroll
        for (int i = 0; i < 4; ++i) a[i] = *(const short8*)(fA + i * 16 * 32);
#pragma unroll
        for (int j = 0; j < 4; ++j) b[j] = *(const short8*)(fB + j * 16 * 32);
#pragma unroll
        for (int i = 0; i < 4; ++i)
#pragma unroll
            for (int j = 0; j < 4; ++j)
                acc[i][j] = __builtin_amdgcn_mfma_f32_16x16x32_bf16(a[i], b[j], acc[i][j], 0, 0, 0);
        __syncthreads();
    }

    // epilogue: C/D layout col=lane&15, row=(lane>>4)*4+reg
    const int er = (lane >> 4) << 2;
    const int ec = lane & 15;
#pragma unroll
    for (int i = 0; i < 4; ++i) {
#pragma unroll
        for (int j = 0; j < 4; ++j) {
            const size_t row0 = (size_t)(bm * 128 + waveM + i * 16 + er);
            const size_t col  = (size_t)(bn * 128 + waveN + j * 16 + ec);
#pragma unroll
            for (int rr = 0; rr < 4; ++rr) {
                C[(row0 + rr) * N_DIM + col] = acc[i][j][rr];
            }
        }
    }
}

// ---------------- fallback GEMM (no workspace): inline-converts x and W ----------------
__global__ __launch_bounds__(256) void gemm_fb(const float* __restrict__ X,
                                               const int* __restrict__ W,
                                               float* __restrict__ C) {
    __shared__ __attribute__((aligned(16))) unsigned short sA[128 * 32];
    __shared__ __attribute__((aligned(16))) unsigned short sB[128 * 32]; // [n][k]

    const int t    = threadIdx.x;
    const int lane = t & 63;
    const int wave = t >> 6;
    const int bn   = blockIdx.x;
    const int bm   = blockIdx.y;
    const int waveM = (wave >> 1) * 64;
    const int waveN = (wave & 1) * 64;

    // A staging: 128 rows x 32 cols fp32; thread: row=t>>1, 16 cols
    const int ar = t >> 1, ac = (t & 1) << 4;
    const float* gX = X + (size_t)(bm * 128 + ar) * K_DIM + ac;
    // B staging: W[k][n] 32 x 128 int32; thread: row=t>>3, 16 cols
    const int br = t >> 3, bc = (t & 7) << 4;
    const int* gW = W + (size_t)br * N_DIM + bn * 128 + bc;

    const int fr = lane & 15;
    const int fk = (lane >> 4) << 3;
    const unsigned short* fA = sA + (waveM + fr) * 32 + fk;
    const unsigned short* fB = sB + (waveN + fr) * 32 + fk;

    floatx4 acc[4][4];
#pragma unroll
    for (int i = 0; i < 4; ++i)
#pragma unroll
        for (int j = 0; j < 4; ++j) acc[i][j] = (floatx4){0.f, 0.f, 0.f, 0.f};

    for (int k0 = 0; k0 < K_DIM; k0 += 32) {
        // A: 4 float4 -> 16 bf16 -> 2x16B LDS writes
        {
            const float4* p = (const float4*)gX;
            float4 v0 = p[0], v1 = p[1], v2 = p[2], v3 = p[3];
            uint4 o0, o1;
            o0.x = (unsigned int)f2bf(v0.x) | ((unsigned int)f2bf(v0.y) << 16);
            o0.y = (unsigned int)f2bf(v0.z) | ((unsigned int)f2bf(v0.w) << 16);
            o0.z = (unsigned int)f2bf(v1.x) | ((unsigned int)f2bf(v1.y) << 16);
            o0.w = (unsigned int)f2bf(v1.z) | ((unsigned int)f2bf(v1.w) << 16);
            o1.x = (unsigned int)f2bf(v2.x) | ((unsigned int)f2bf(v2.y) << 16);
            o1.y = (unsigned int)f2bf(v2.z) | ((unsigned int)f2bf(v2.w) << 16);
            o1.z = (unsigned int)f2bf(v3.x) | ((unsigned int)f2bf(v3.y) << 16);
            o1.w = (unsigned int)f2bf(v3.z) | ((unsigned int)f2bf(v3.w) << 16);
            uint4* d = (uint4*)&sA[ar * 32 + ac];
            d[0] = o0; d[1] = o1;
        }
        // B: 16 int32 -> bf16, transposed scatter into sB[n][k]
        {
#pragma unroll
            for (int q = 0; q < 4; ++q) {
                int4 v = ((const int4*)gW)[q];
                sB[(bc + q * 4 + 0) * 32 + br] = f2bf((float)v.x);
                sB[(bc + q * 4 + 1) * 32 + br] = f2bf((float)v.y);
                sB[(bc + q * 4 + 2) * 32 + br] = f2bf((float)v.z);
                sB[(bc + q * 4 + 3) * 32 + br] = f2bf((float)v.w);
            }
        }
        gX += 32;
        gW += (size_t)32 * N_DIM;
        __syncthreads();

        short8 a[4], b[4];
#pragma unroll
        for (int i = 0; i < 4; ++i) a[i] = *(const short8*)(fA + i * 16 * 32);
#pragma unroll
        for (int j = 0; j < 4; ++j) b[j] = *(const short8*)(fB + j * 16 * 32);
#pragma unroll
        for (int i = 0; i < 4; ++i)
#pragma unroll
            for (int j = 0; j < 4; ++j)
                acc[i][j] = __builtin_amdgcn_mfma_f32_16x16x32_bf16(a[i], b[j], acc[i][j], 0, 0, 0);
        __syncthreads();
    }

    const int er = (lane >> 4) << 2;
    const int ec = lane & 15;
#pragma unroll
    for (int i = 0; i < 4; ++i)
#pragma unroll
        for (int j = 0; j < 4; ++j) {
            const size_t row0 = (size_t)(bm * 128 + waveM + i * 16 + er);
            const size_t col  = (size_t)(bn * 128 + waveN + j * 16 + ec);
#pragma unroll
            for (int rr = 0; rr < 4; ++rr) C[(row0 + rr) * N_DIM + col] = acc[i][j][rr];
        }
}

extern "C" void kernel_launch(void* const* d_in, const int* in_sizes, int n_in,
                              void* d_out, int out_size, void* d_ws, size_t ws_size,
                              hipStream_t stream) {
    const float* x = (const float*)d_in[0];
    const int*   w = (const int*)d_in[1];     // int8-range values in int32 container
    float* out = (float*)d_out;

    const size_t bytesA = (size_t)M_DIM * K_DIM * 2;  // x as bf16: 64 MiB
    const size_t bytesB = (size_t)K_DIM * N_DIM * 2;  // W^T as bf16: 32 MiB

    if (ws_size >= bytesA + bytesB) {
        unsigned short* Abf = (unsigned short*)d_ws;
        unsigned short* WT  = (unsigned short*)((char*)d_ws + bytesA);
        cvt_x_kernel<<<(M_DIM * (size_t)K_DIM) / 8 / 256, 256, 0, stream>>>(x, Abf);
        wt_cvt_kernel<<<dim3(N_DIM / 64, K_DIM / 64), 256, 0, stream>>>(w, WT);
        gemm_pp<<<dim3(N_DIM / 128, M_DIM / 128), 256, 0, stream>>>(Abf, WT, out);
    } else {
        gemm_fb<<<dim3(N_DIM / 128, M_DIM / 128), 256, 0, stream>>>(x, w, out);
    }
}

// Round 2
// 432.232 us; speedup vs baseline: 1.4560x; 1.4560x over previous
//
#include <hip/hip_runtime.h>
#include <hip/hip_bf16.h>

// out[8192,4096] fp32 = x[8192,4096] fp32 @ W[4096,4096] (int8 in int32 container)
// Path: per-row int8 quantize x (exact int8 weights) -> i8 MFMA GEMM -> fp32 scale epilogue.
#define M_DIM 8192
#define N_DIM 4096
#define K_DIM 4096

typedef __attribute__((ext_vector_type(4))) int int4v;
typedef __attribute__((ext_vector_type(8))) short short8;
typedef __attribute__((ext_vector_type(4))) float floatx4;

__device__ __forceinline__ unsigned short f2bf(float f) {
    union { float f; unsigned int u; } cv; cv.f = f;
    unsigned int u = cv.u;
    return (unsigned short)((u + 0x7fffu + ((u >> 16) & 1u)) >> 16);
}

// ---------------- pre-pass 1: x fp32 -> int8 (per-row absmax scale) ----------------
__global__ __launch_bounds__(256) void xq_kernel(const float* __restrict__ X,
                                                 char* __restrict__ Xq,
                                                 float* __restrict__ scales) {
    const int row = blockIdx.x;
    const int t = threadIdx.x;
    const float4* src = (const float4*)(X + (size_t)row * K_DIM);
    float4 v[4];
    float am = 0.f;
#pragma unroll
    for (int i = 0; i < 4; ++i) {
        v[i] = src[t + i * 256];
        am = fmaxf(am, fmaxf(fmaxf(fabsf(v[i].x), fabsf(v[i].y)),
                             fmaxf(fabsf(v[i].z), fabsf(v[i].w))));
    }
    // wave reduce (64 lanes), then cross-wave via LDS
#pragma unroll
    for (int off = 32; off; off >>= 1) am = fmaxf(am, __shfl_xor(am, off, 64));
    __shared__ float wmax[4];
    if ((t & 63) == 0) wmax[t >> 6] = am;
    __syncthreads();
    am = fmaxf(fmaxf(wmax[0], wmax[1]), fmaxf(wmax[2], wmax[3]));
    am = fmaxf(am, 1e-20f);
    const float inv = 127.f / am;
    unsigned int* dst = (unsigned int*)(Xq + (size_t)row * K_DIM);
#pragma unroll
    for (int i = 0; i < 4; ++i) {
        int q0 = __float2int_rn(v[i].x * inv);
        int q1 = __float2int_rn(v[i].y * inv);
        int q2 = __float2int_rn(v[i].z * inv);
        int q3 = __float2int_rn(v[i].w * inv);
        dst[t + i * 256] = (unsigned int)(q0 & 255) | ((unsigned int)(q1 & 255) << 8) |
                           ((unsigned int)(q2 & 255) << 16) | ((unsigned int)q3 << 24);
    }
    if (t == 0) scales[row] = am * (1.f / 127.f);
}

// ---------------- pre-pass 2: W int32 [K][N] -> int8 W^T [N][K] ----------------
__global__ __launch_bounds__(256) void wq_kernel(const int* __restrict__ W,
                                                 char* __restrict__ WT) {
    __shared__ int trans[64][17];   // [n_local][k_local/4], pitch 17 (gcd(17,32)=1 -> conflict-free)
    const int t  = threadIdx.x;
    const int tn = blockIdx.x;      // N/64
    const int tk = blockIdx.y;      // K/64
    const int n  = t & 63;
    const int kg = t >> 6;          // 0..3

#pragma unroll
    for (int p = 0; p < 4; ++p) {
        const int kb = p * 16 + kg * 4;   // k_local base, multiple of 4
        const int* src = W + (size_t)(tk * 64 + kb) * N_DIM + tn * 64 + n;
        int v0 = src[0];
        int v1 = src[N_DIM];
        int v2 = src[2 * N_DIM];
        int v3 = src[3 * N_DIM];
        trans[n][kb >> 2] = (v0 & 255) | ((v1 & 255) << 8) | ((v2 & 255) << 16) |
                            ((unsigned int)v3 << 24);
    }
    __syncthreads();

    const int n2 = t >> 2;          // 0..63
    const int c  = t & 3;           // 16-byte chunk
    int o0 = trans[n2][c * 4 + 0];
    int o1 = trans[n2][c * 4 + 1];
    int o2 = trans[n2][c * 4 + 2];
    int o3 = trans[n2][c * 4 + 3];
    char* dst = WT + (size_t)(tn * 64 + n2) * K_DIM + tk * 64 + c * 16;
    int4 o; o.x = o0; o.y = o1; o.z = o2; o.w = o3;
    *(int4*)dst = o;
}

// ---------------- main GEMM: A int8 [M][K], BT int8 [N][K], i8 MFMA ----------------
__global__ __launch_bounds__(256) void gemm_i8(const char* __restrict__ A,
                                               const char* __restrict__ BT,
                                               const float* __restrict__ scales,
                                               float* __restrict__ C) {
    __shared__ __attribute__((aligned(16))) char sA[128 * 64];  // 128 rows x 64 bytes (BK=64)
    __shared__ __attribute__((aligned(16))) char sB[128 * 64];

    const int t    = threadIdx.x;
    const int lane = t & 63;
    const int wave = t >> 6;
    const int bn   = blockIdx.x;   // N/128 = 32
    const int bm   = blockIdx.y;   // M/128 = 64
    const int waveM = (wave >> 1) * 64;
    const int waveN = (wave & 1) * 64;

    // staging: row sr (0..63 / +64), 16B chunk sc
    const int sr = t >> 2;
    const int sc = (t & 3) << 4;
    const char* gA0 = A + (size_t)(bm * 128 + sr) * K_DIM + sc;
    const char* gA1 = gA0 + (size_t)64 * K_DIM;
    const char* gB0 = BT + (size_t)(bn * 128 + sr) * K_DIM + sc;
    const char* gB1 = gB0 + (size_t)64 * K_DIM;
    // wave-uniform LDS dests (HW adds lane*16); wave w covers rows 16w..16w+15 = 1024 B
    char* lA0 = sA + wave * 1024;
    char* lA1 = sA + 4096 + wave * 1024;
    char* lB0 = sB + wave * 1024;
    char* lB1 = sB + 4096 + wave * 1024;

    // fragment read addresses: lane l -> m/n = l&15, k = (l>>4)*16 .. +15
    const int fr = lane & 15;
    const int fk = (lane >> 4) << 4;
    const char* fA = sA + (waveM + fr) * 64 + fk;
    const char* fB = sB + (waveN + fr) * 64 + fk;

    int4v acc[4][4];
#pragma unroll
    for (int i = 0; i < 4; ++i)
#pragma unroll
        for (int j = 0; j < 4; ++j) acc[i][j] = (int4v){0, 0, 0, 0};

    for (int k0 = 0; k0 < K_DIM; k0 += 64) {
        __builtin_amdgcn_global_load_lds((const __attribute__((address_space(1))) void*)gA0,
                                         (__attribute__((address_space(3))) void*)lA0, 16, 0, 0);
        __builtin_amdgcn_global_load_lds((const __attribute__((address_space(1))) void*)gA1,
                                         (__attribute__((address_space(3))) void*)lA1, 16, 0, 0);
        __builtin_amdgcn_global_load_lds((const __attribute__((address_space(1))) void*)gB0,
                                         (__attribute__((address_space(3))) void*)lB0, 16, 0, 0);
        __builtin_amdgcn_global_load_lds((const __attribute__((address_space(1))) void*)gB1,
                                         (__attribute__((address_space(3))) void*)lB1, 16, 0, 0);
        gA0 += 64; gA1 += 64; gB0 += 64; gB1 += 64;
        __syncthreads();

        int4v a[4], b[4];
#pragma unroll
        for (int i = 0; i < 4; ++i) a[i] = *(const int4v*)(fA + i * 16 * 64);
#pragma unroll
        for (int j = 0; j < 4; ++j) b[j] = *(const int4v*)(fB + j * 16 * 64);
#pragma unroll
        for (int i = 0; i < 4; ++i)
#pragma unroll
            for (int j = 0; j < 4; ++j)
                acc[i][j] = __builtin_amdgcn_mfma_i32_16x16x64_i8(a[i], b[j], acc[i][j], 0, 0, 0);
        __syncthreads();
    }

    // epilogue: C/D layout col=lane&15, row=(lane>>4)*4+reg; out = acc * scale[row]
    const int er = (lane >> 4) << 2;
    const int ec = lane & 15;
#pragma unroll
    for (int i = 0; i < 4; ++i) {
        const size_t row0 = (size_t)(bm * 128 + waveM + i * 16 + er);
        const float4 s4 = *(const float4*)(scales + row0);   // rows row0..row0+3
        const float sc4[4] = {s4.x, s4.y, s4.z, s4.w};
#pragma unroll
        for (int j = 0; j < 4; ++j) {
            const size_t col = (size_t)(bn * 128 + waveN + j * 16 + ec);
#pragma unroll
            for (int rr = 0; rr < 4; ++rr) {
                C[(row0 + rr) * N_DIM + col] = (float)acc[i][j][rr] * sc4[rr];
            }
        }
    }
}

// ---------------- fallback GEMM (no workspace): bf16, inline-converts x and W ----------------
__global__ __launch_bounds__(256) void gemm_fb(const float* __restrict__ X,
                                               const int* __restrict__ W,
                                               float* __restrict__ C) {
    __shared__ __attribute__((aligned(16))) unsigned short sA[128 * 32];
    __shared__ __attribute__((aligned(16))) unsigned short sB[128 * 32];

    const int t    = threadIdx.x;
    const int lane = t & 63;
    const int wave = t >> 6;
    const int bn   = blockIdx.x;
    const int bm   = blockIdx.y;
    const int waveM = (wave >> 1) * 64;
    const int waveN = (wave & 1) * 64;

    const int ar = t >> 1, ac = (t & 1) << 4;
    const float* gX = X + (size_t)(bm * 128 + ar) * K_DIM + ac;
    const int br = t >> 3, bc = (t & 7) << 4;
    const int* gW = W + (size_t)br * N_DIM + bn * 128 + bc;

    const int fr = lane & 15;
    const int fk = (lane >> 4) << 3;
    const unsigned short* fA = sA + (waveM + fr) * 32 + fk;
    const unsigned short* fB = sB + (waveN + fr) * 32 + fk;

    floatx4 acc[4][4];
#pragma unroll
    for (int i = 0; i < 4; ++i)
#pragma unroll
        for (int j = 0; j < 4; ++j) acc[i][j] = (floatx4){0.f, 0.f, 0.f, 0.f};

    for (int k0 = 0; k0 < K_DIM; k0 += 32) {
        {
            const float4* p = (const float4*)gX;
            float4 v0 = p[0], v1 = p[1], v2 = p[2], v3 = p[3];
            uint4 o0, o1;
            o0.x = (unsigned int)f2bf(v0.x) | ((unsigned int)f2bf(v0.y) << 16);
            o0.y = (unsigned int)f2bf(v0.z) | ((unsigned int)f2bf(v0.w) << 16);
            o0.z = (unsigned int)f2bf(v1.x) | ((unsigned int)f2bf(v1.y) << 16);
            o0.w = (unsigned int)f2bf(v1.z) | ((unsigned int)f2bf(v1.w) << 16);
            o1.x = (unsigned int)f2bf(v2.x) | ((unsigned int)f2bf(v2.y) << 16);
            o1.y = (unsigned int)f2bf(v2.z) | ((unsigned int)f2bf(v2.w) << 16);
            o1.z = (unsigned int)f2bf(v3.x) | ((unsigned int)f2bf(v3.y) << 16);
            o1.w = (unsigned int)f2bf(v3.z) | ((unsigned int)f2bf(v3.w) << 16);
            uint4* d = (uint4*)&sA[ar * 32 + ac];
            d[0] = o0; d[1] = o1;
        }
        {
#pragma unroll
            for (int q = 0; q < 4; ++q) {
                int4 v = ((const int4*)gW)[q];
                sB[(bc + q * 4 + 0) * 32 + br] = f2bf((float)v.x);
                sB[(bc + q * 4 + 1) * 32 + br] = f2bf((float)v.y);
                sB[(bc + q * 4 + 2) * 32 + br] = f2bf((float)v.z);
                sB[(bc + q * 4 + 3) * 32 + br] = f2bf((float)v.w);
            }
        }
        gX += 32;
        gW += (size_t)32 * N_DIM;
        __syncthreads();

        short8 a[4], b[4];
#pragma unroll
        for (int i = 0; i < 4; ++i) a[i] = *(const short8*)(fA + i * 16 * 32);
#pragma unroll
        for (int j = 0; j < 4; ++j) b[j] = *(const short8*)(fB + j * 16 * 32);
#pragma unroll
        for (int i = 0; i < 4; ++i)
#pragma unroll
            for (int j = 0; j < 4; ++j)
                acc[i][j] = __builtin_amdgcn_mfma_f32_16x16x32_bf16(a[i], b[j], acc[i][j], 0, 0, 0);
        __syncthreads();
    }

    const int er = (lane >> 4) << 2;
    const int ec = lane & 15;
#pragma unroll
    for (int i = 0; i < 4; ++i)
#pragma unroll
        for (int j = 0; j < 4; ++j) {
            const size_t row0 = (size_t)(bm * 128 + waveM + i * 16 + er);
            const size_t col  = (size_t)(bn * 128 + waveN + j * 16 + ec);
#pragma unroll
            for (int rr = 0; rr < 4; ++rr) C[(row0 + rr) * N_DIM + col] = acc[i][j][rr];
        }
}

extern "C" void kernel_launch(void* const* d_in, const int* in_sizes, int n_in,
                              void* d_out, int out_size, void* d_ws, size_t ws_size,
                              hipStream_t stream) {
    const float* x = (const float*)d_in[0];
    const int*   w = (const int*)d_in[1];
    float* out = (float*)d_out;

    const size_t bytesXq = (size_t)M_DIM * K_DIM;        // 32 MiB
    const size_t bytesWT = (size_t)K_DIM * N_DIM;        // 16 MiB
    const size_t bytesSc = (size_t)M_DIM * sizeof(float);

    if (ws_size >= bytesXq + bytesWT + bytesSc) {
        char*  Xq = (char*)d_ws;
        char*  WT = (char*)d_ws + bytesXq;
        float* Sc = (float*)((char*)d_ws + bytesXq + bytesWT);
        xq_kernel<<<M_DIM, 256, 0, stream>>>(x, Xq, Sc);
        wq_kernel<<<dim3(N_DIM / 64, K_DIM / 64), 256, 0, stream>>>(w, WT);
        gemm_i8<<<dim3(N_DIM / 128, M_DIM / 128), 256, 0, stream>>>(Xq, WT, Sc, out);
    } else {
        gemm_fb<<<dim3(N_DIM / 128, M_DIM / 128), 256, 0, stream>>>(x, w, out);
    }
}